// Round 23
// baseline (354.848 us; speedup 1.0000x reference)
//
#include <hip/hip_runtime.h>
#include <hip/hip_bf16.h>

#define BB 2
#define NN 512
#define LL 8192
#define CC 256
#define HH 8
#define DD 32
#define SCALE 0.17677669529663687f

typedef unsigned short u16;
typedef unsigned int u32;
typedef __attribute__((ext_vector_type(8))) short bf16x8;
typedef __attribute__((ext_vector_type(4))) float f32x4;

__device__ __forceinline__ float bf2f(u16 v) { return __uint_as_float(((u32)v) << 16); }
__device__ __forceinline__ u16 f2bf(float f) {
    u32 u = __float_as_uint(f);
    return (u16)((u + 0x7fffu + ((u >> 16) & 1u)) >> 16);
}
__device__ __forceinline__ bf16x8 ld8(const u16* p) { return *(const bf16x8*)p; }
__device__ __forceinline__ bf16x8 cvt8(float4 a, float4 b) {
    bf16x8 r;
    r[0] = (short)f2bf(a.x); r[1] = (short)f2bf(a.y);
    r[2] = (short)f2bf(a.z); r[3] = (short)f2bf(a.w);
    r[4] = (short)f2bf(b.x); r[5] = (short)f2bf(b.y);
    r[6] = (short)f2bf(b.z); r[7] = (short)f2bf(b.w);
    return r;
}

__global__ void sentinel(float* out, float val) {
    if (threadIdx.x == 0) out[0] = val;
}

// ---------------------------------------------------------------------------
// MFMA GEMM (bf16 operands in-register from f32 inputs, f32 accum + f32
// epilogue): C[M,N] = A[M,K] @ W[N,K]^T (+bias)(+res)(+gelu). LDS-free.
// Block = 4 waves; wave = 16 rows x 64 cols. Fragment mapping r20/r21-proven.
// OUT: 0 f32, 1 bf16, 2 both.
// ---------------------------------------------------------------------------
template <int RES, int ACT, bool HAS_BIAS, int OUT>
__global__ __launch_bounds__(256) void gemm_mfma(
    const float* __restrict__ A, const float* __restrict__ W,
    const float* __restrict__ bias, const float* __restrict__ res,
    float* __restrict__ Cf, u16* __restrict__ Cb, int M, int N, int K)
{
    int lane = threadIdx.x & 63, wave = threadIdx.x >> 6;
    int lr = lane & 15, lg = lane >> 4;
    int m0 = blockIdx.x * 64 + wave * 16;
    int n0 = blockIdx.y * 64;
    f32x4 acc[4] = {};
    const float* Ab = A + (size_t)(m0 + lr) * K + lg * 8;
    for (int k0 = 0; k0 < K; k0 += 32) {
        bf16x8 af = cvt8(*(const float4*)(Ab + k0), *(const float4*)(Ab + k0 + 4));
#pragma unroll
        for (int nt = 0; nt < 4; ++nt) {
            const float* Wb = W + (size_t)(n0 + nt * 16 + lr) * K + lg * 8 + k0;
            bf16x8 wf = cvt8(*(const float4*)Wb, *(const float4*)(Wb + 4));
            acc[nt] = __builtin_amdgcn_mfma_f32_16x16x32_bf16(af, wf, acc[nt], 0, 0, 0);
        }
    }
#pragma unroll
    for (int nt = 0; nt < 4; ++nt) {
        int col = n0 + nt * 16 + lr;
        float bv = HAS_BIAS ? bias[col] : 0.f;
#pragma unroll
        for (int r = 0; r < 4; ++r) {
            int row = m0 + lg * 4 + r;
            float v = acc[nt][r] + bv;
            if (RES) v += res[(size_t)row * N + col];
            if (ACT) v = 0.5f * v * (1.f + erff(v * 0.70710678118f));
            if (OUT == 0 || OUT == 2) Cf[(size_t)row * N + col] = v;
            if (OUT == 1 || OUT == 2) Cb[(size_t)row * N + col] = f2bf(v);
        }
    }
}

// ---------------------------------------------------------------------------
// bf16 head-transpose (r20 proven).
// ---------------------------------------------------------------------------
__global__ __launch_bounds__(256) void transpose_bf(
    const u16* __restrict__ in, u16* __restrict__ out,
    int rowStride, int vtL, size_t bStrideIn, size_t bStrideOut)
{
    __shared__ alignas(16) u16 tl[64][33];
    int r0 = blockIdx.x * 64;
    int h = blockIdx.y, b = blockIdx.z;
    const u16* ip = in + (size_t)b * bStrideIn + h * DD;
    for (int i = threadIdx.x; i < 64 * 32; i += 256) {
        int r = i >> 5, d = i & 31;
        tl[r][d] = ip[(size_t)(r0 + r) * rowStride + d];
    }
    __syncthreads();
    u16* op = out + (size_t)b * bStrideOut + (size_t)h * DD * vtL + r0;
    for (int i = threadIdx.x; i < 64 * 32; i += 256) {
        int r = i & 63, d = i >> 6;
        op[(size_t)d * vtL + r] = tl[r][d];
    }
}

// ---------------------------------------------------------------------------
// MFMA flash attention (r20 proven).
// ---------------------------------------------------------------------------
template <bool SPLIT>
__global__ __launch_bounds__(256) void attn_mfma(
    const u16* __restrict__ qp, const u16* __restrict__ kp,
    const u16* __restrict__ vt, float* __restrict__ outp,
    float* __restrict__ pm, float* __restrict__ ps_,
    int Lk, int qStride, int kStride, int vtL, int Nq)
{
    __shared__ alignas(16) u16 plds[4][32][48];
    __shared__ alignas(16) float comb[4][32][34];
    int lane = threadIdx.x & 63, wave = threadIdx.x >> 6;
    int lr = lane & 15, lg = lane >> 4;
    int h = blockIdx.y, n0 = blockIdx.x * 32, z = blockIdx.z;
    size_t qoff = 0, koff = 0, voff = 0;
    int lbeg, lend;
    if (SPLIT) {
        int chunk = Lk / (gridDim.z * 4);
        lbeg = z * (Lk / gridDim.z) + wave * chunk;
        lend = lbeg + chunk;
    } else {
        int chunk = Lk / 4;
        lbeg = wave * chunk;
        lend = lbeg + chunk;
        qoff = (size_t)z * Nq * qStride;
        koff = (size_t)z * Lk * kStride;
        voff = (size_t)z * HH * DD * vtL;
    }

    bf16x8 bq[2];
#pragma unroll
    for (int nh = 0; nh < 2; ++nh)
        bq[nh] = ld8(qp + qoff + (size_t)(n0 + nh * 16 + lr) * qStride + h * DD + lg * 8);

    f32x4 o[2][2] = {};
    float m = -1e30f, s = 0.f;
    float m2 = -1e30f, s2 = 0.f;
    const u16* kb = kp + koff + h * DD + lg * 8;
    const u16* vb0 = vt + voff + (size_t)h * DD * vtL;

    for (int l0 = lbeg; l0 < lend; l0 += 32) {
        bf16x8 ka[2];
#pragma unroll
        for (int lt = 0; lt < 2; ++lt)
            ka[lt] = ld8(kb + (size_t)(l0 + lt * 16 + lr) * kStride);
        f32x4 st[2][2];
#pragma unroll
        for (int lt = 0; lt < 2; ++lt)
#pragma unroll
            for (int nh = 0; nh < 2; ++nh) {
                f32x4 zz = {0.f, 0.f, 0.f, 0.f};
                st[lt][nh] = __builtin_amdgcn_mfma_f32_16x16x32_bf16(ka[lt], bq[nh], zz, 0, 0, 0);
            }
        float aq[2];
#pragma unroll
        for (int nh = 0; nh < 2; ++nh) {
            float mprev = (nh == 0) ? m : m2;
            float sprev = (nh == 0) ? s : s2;
            float mx = -1e30f;
#pragma unroll
            for (int lt = 0; lt < 2; ++lt)
#pragma unroll
                for (int r = 0; r < 4; ++r) {
                    float v = st[lt][nh][r] * SCALE;
                    st[lt][nh][r] = v;
                    mx = fmaxf(mx, v);
                }
            mx = fmaxf(mx, __shfl_xor(mx, 16));
            mx = fmaxf(mx, __shfl_xor(mx, 32));
            float mn = fmaxf(mprev, mx);
            float alpha = __expf(mprev - mn);
            float rs = 0.f;
#pragma unroll
            for (int lt = 0; lt < 2; ++lt) {
                u16 pk[4];
#pragma unroll
                for (int r = 0; r < 4; ++r) {
                    float p = __expf(st[lt][nh][r] - mn);
                    rs += p;
                    pk[r] = f2bf(p);
                }
                uint2 pv;
                pv.x = (u32)pk[0] | ((u32)pk[1] << 16);
                pv.y = (u32)pk[2] | ((u32)pk[3] << 16);
                *(uint2*)&plds[wave][nh * 16 + lr][lt * 16 + lg * 4] = pv;
            }
            rs += __shfl_xor(rs, 16);
            rs += __shfl_xor(rs, 32);
            if (nh == 0) { s = sprev * alpha + rs; m = mn; }
            else         { s2 = sprev * alpha + rs; m2 = mn; }
            aq[nh] = alpha;
        }
#pragma unroll
        for (int qt = 0; qt < 2; ++qt)
#pragma unroll
            for (int r = 0; r < 4; ++r) {
                float al = __shfl(aq[qt], (lg << 2) + r);
                o[qt][0][r] *= al;
                o[qt][1][r] *= al;
            }
        asm volatile("" ::: "memory");
        bf16x8 pa[2], vv[2];
#pragma unroll
        for (int qt = 0; qt < 2; ++qt)
            pa[qt] = ld8(&plds[wave][qt * 16 + lr][lg * 8]);
        asm volatile("" ::: "memory");
#pragma unroll
        for (int dt = 0; dt < 2; ++dt)
            vv[dt] = ld8(vb0 + (size_t)(dt * 16 + lr) * vtL + l0 + lg * 8);
#pragma unroll
        for (int qt = 0; qt < 2; ++qt)
#pragma unroll
            for (int dt = 0; dt < 2; ++dt)
                o[qt][dt] = __builtin_amdgcn_mfma_f32_16x16x32_bf16(pa[qt], vv[dt], o[qt][dt], 0, 0, 0);
    }

#pragma unroll
    for (int qt = 0; qt < 2; ++qt)
#pragma unroll
        for (int dt = 0; dt < 2; ++dt)
#pragma unroll
            for (int r = 0; r < 4; ++r)
                comb[wave][qt * 16 + lg * 4 + r][dt * 16 + lr] = o[qt][dt][r];
    if (lg == 0) {
        comb[wave][lr][32] = m;       comb[wave][lr][33] = s;
        comb[wave][16 + lr][32] = m2; comb[wave][16 + lr][33] = s2;
    }
    __syncthreads();
    for (int idx = threadIdx.x; idx < 1024; idx += 256) {
        int q2 = idx >> 5, d = idx & 31;
        float mm = -1e30f;
#pragma unroll
        for (int w = 0; w < 4; ++w) mm = fmaxf(mm, comb[w][q2][32]);
        float num = 0.f, den = 0.f;
#pragma unroll
        for (int w = 0; w < 4; ++w) {
            float e = __expf(comb[w][q2][32] - mm);
            num += e * comb[w][q2][d];
            den += e * comb[w][q2][33];
        }
        int n = n0 + q2;
        if (SPLIT) {
            outp[((size_t)z * Nq + n) * CC + h * DD + d] = num;
            if (d == 0) {
                pm[((size_t)z * Nq + n) * HH + h] = mm;
                ps_[((size_t)z * Nq + n) * HH + h] = den;
            }
        } else {
            outp[((size_t)z * Nq + n) * CC + h * DD + d] = num / den;
        }
    }
}

// ---------------------------------------------------------------------------
// Combine flash partials (r19/r20 proven).
// ---------------------------------------------------------------------------
__global__ __launch_bounds__(256) void attn_combine(
    const float* __restrict__ po, const float* __restrict__ pm,
    const float* __restrict__ ps, float* __restrict__ out,
    int Nq, int nsplit)
{
    int idx = blockIdx.x * 256 + threadIdx.x;
    if (idx >= Nq * CC) return;
    int n = idx >> 8, cd = idx & 255;
    int h = cd >> 5;
    float mm = -1e30f;
    for (int zz = 0; zz < nsplit; ++zz)
        mm = fmaxf(mm, pm[((size_t)zz * Nq + n) * HH + h]);
    float num = 0.f, den = 0.f;
    for (int zz = 0; zz < nsplit; ++zz) {
        float e = __expf(pm[((size_t)zz * Nq + n) * HH + h] - mm);
        num += e * po[((size_t)zz * Nq + n) * CC + cd];
        den += e * ps[((size_t)zz * Nq + n) * HH + h];
    }
    out[(size_t)n * CC + cd] = num / den;
}

// ---------------------------------------------------------------------------
// MFMA mask (r21 proven).
// ---------------------------------------------------------------------------
template <int NL>
__global__ __launch_bounds__(256) void smask_mfma(
    const u16* __restrict__ qcb, const u16* __restrict__ kcb,
    const float* __restrict__ w1, const float* __restrict__ b1,
    const float* __restrict__ w2, const float* __restrict__ b2,
    float* __restrict__ mout)
{
    int lane = threadIdx.x & 63, wave = threadIdx.x >> 6;
    int lr = lane & 15, lg = lane >> 4;
    int n0 = blockIdx.y * 32;
    bf16x8 bq[8][2];
#pragma unroll
    for (int h = 0; h < 8; ++h)
#pragma unroll
        for (int nh = 0; nh < 2; ++nh)
            bq[h][nh] = ld8(qcb + (size_t)(n0 + nh * 16 + lr) * CC + h * DD + lg * 8);
    float b2v = b2[0];
    for (int it = 0; it < NL; ++it) {
        int l0 = (blockIdx.x * NL + it) * 64 + wave * 16;
        bf16x8 ka[8];
#pragma unroll
        for (int h = 0; h < 8; ++h)
            ka[h] = ld8(kcb + (size_t)(l0 + lr) * CC + h * DD + lg * 8);
#pragma unroll
        for (int nh = 0; nh < 2; ++nh) {
            f32x4 st[8];
#pragma unroll
            for (int h = 0; h < 8; ++h) {
                f32x4 zz = {0.f, 0.f, 0.f, 0.f};
                st[h] = __builtin_amdgcn_mfma_f32_16x16x32_bf16(ka[h], bq[h][nh], zz, 0, 0, 0);
            }
            float4 res;
            float* rp = &res.x;
#pragma unroll
            for (int r = 0; r < 4; ++r) {
                float s[8];
#pragma unroll
                for (int i = 0; i < 8; ++i) s[i] = st[i][r] * SCALE;
                float acc2 = b2v;
#pragma unroll
                for (int o = 0; o < 8; ++o) {
                    float f = b1[o];
#pragma unroll
                    for (int i = 0; i < 8; ++i) f += s[i] * w1[o * 8 + i];
                    f = fmaxf(f, 0.f);
                    acc2 += f * w2[o];
                }
                rp[r] = fmaxf(acc2, 0.f);
            }
            *(float4*)&mout[(size_t)(n0 + nh * 16 + lr) * LL + l0 + lg * 4] = res;
        }
    }
}

// ---------------------------------------------------------------------------
// f32 LayerNorm over C=256 (r17 proven).
// ---------------------------------------------------------------------------
__global__ __launch_bounds__(256) void ln_f32(
    const float* __restrict__ a, const float* __restrict__ g,
    const float* __restrict__ be, float* __restrict__ out)
{
    int lane = threadIdx.x & 63, wave = threadIdx.x >> 6;
    int row = blockIdx.x * 4 + wave;
    float4 v = *(const float4*)(a + (size_t)row * CC + lane * 4);
    float sum = v.x + v.y + v.z + v.w;
    float sq = v.x * v.x + v.y * v.y + v.z * v.z + v.w * v.w;
#pragma unroll
    for (int mk = 1; mk < 64; mk <<= 1) {
        sum += __shfl_xor(sum, mk);
        sq += __shfl_xor(sq, mk);
    }
    float mean = sum * (1.f / 256.f);
    float var = sq * (1.f / 256.f) - mean * mean;
    float rstd = rsqrtf(var + 1e-5f);
    int c = lane * 4;
    float4 ov;
    ov.x = (v.x - mean) * rstd * g[c + 0] + be[c + 0];
    ov.y = (v.y - mean) * rstd * g[c + 1] + be[c + 1];
    ov.z = (v.z - mean) * rstd * g[c + 2] + be[c + 2];
    ov.w = (v.w - mean) * rstd * g[c + 3] + be[c + 3];
    *(float4*)(out + (size_t)row * CC + c) = ov;
}

// ---------------------------------------------------------------------------
extern "C" void kernel_launch(void* const* d_in, const int* in_sizes, int n_in,
                              void* d_out, int out_size, void* d_ws, size_t ws_size,
                              hipStream_t stream)
{
    (void)in_sizes; (void)n_in; (void)out_size;
    float* outx = (float*)d_out;
    float* outm = outx + (size_t)BB * NN * CC;

    const float* query     = (const float*)d_in[0];
    const float* key       = (const float*)d_in[1];
    const float* value     = (const float*)d_in[2];
    const float* sa_qkv_w  = (const float*)d_in[3];
    const float* sa_proj_w = (const float*)d_in[4];
    const float* sa_proj_b = (const float*)d_in[5];
    const float* norm3_g   = (const float*)d_in[6];
    const float* norm3_b   = (const float*)d_in[7];
    const float* q_w       = (const float*)d_in[8];
    const float* k_w       = (const float*)d_in[9];
    const float* v_w       = (const float*)d_in[10];
    const float* ca_proj_w = (const float*)d_in[11];
    const float* ca_proj_b = (const float*)d_in[12];
    const float* l1_w      = (const float*)d_in[13];
    const float* l1_b      = (const float*)d_in[14];
    const float* l2_w      = (const float*)d_in[15];
    const float* l2_b      = (const float*)d_in[16];
    const float* ln1_g     = (const float*)d_in[17];
    const float* ln1_b     = (const float*)d_in[18];
    const float* ln2_g     = (const float*)d_in[19];
    const float* ln2_b     = (const float*)d_in[20];
    const float* fc1_w     = (const float*)d_in[21];
    const float* fc1_b     = (const float*)d_in[22];
    const float* fc2_w     = (const float*)d_in[23];
    const float* fc2_b     = (const float*)d_in[24];

    const int NSPLIT = 8;

    char* w0 = (char*)d_ws;
    char* unionA = w0;                 w0 += (size_t)16 * 1024 * 1024;
    float* saH = (float*)w0;           w0 += (size_t)1024 * 256 * 4;
    float* x1  = (float*)w0;           w0 += (size_t)1024 * 256 * 4;
    float* x2  = (float*)w0;           w0 += (size_t)1024 * 256 * 4;
    float* tmp = (float*)w0;           w0 += (size_t)1024 * 256 * 4;
    float* caH = (float*)w0;           w0 += (size_t)1024 * 256 * 4;
    u16*   qc_b = (u16*)w0;            w0 += (size_t)1024 * 256 * 2;
    float* po  = (float*)w0;           w0 += (size_t)NSPLIT * 512 * 256 * 4;
    float* pm  = (float*)w0;           w0 += (size_t)NSPLIT * 512 * 8 * 4;
    float* ps  = (float*)w0;           w0 += (size_t)NSPLIT * 512 * 8 * 4;
    size_t need = (size_t)(w0 - (char*)d_ws);
    u16* qkv_b = (u16*)unionA;                                   // 1024 x 768
    u16* vst   = (u16*)(unionA + (size_t)1024 * 768 * 2);        // (B,H,D,512)
    u16* kc_b  = (u16*)unionA;                                   // 8192 x 256
    u16* vc_b  = (u16*)(unionA + (size_t)8192 * 256 * 2);        // 8192 x 256
    u16* vt_b  = (u16*)(unionA + (size_t)2 * 8192 * 256 * 2);    // (H,D,8192)
    float* hb  = (float*)unionA;                                 // 1024 x 1024

    if (ws_size < need) {
        sentinel<<<dim3(1), dim3(64), 0, stream>>>(outx, 1000.f + (float)(ws_size >> 20));
        return;
    }

    dim3 blk(256);

    // 1. qkv (bf16) = query @ sa_qkv_w.T   [MFMA]
    gemm_mfma<0, 0, false, 1><<<dim3(16, 12), blk, 0, stream>>>(query, sa_qkv_w, nullptr, nullptr, nullptr, qkv_b, 1024, 768, 256);
    // 2. self V^T
    transpose_bf<<<dim3(8, 8, 2), blk, 0, stream>>>(qkv_b + 512, vst, 768, 512, (size_t)512 * 768, (size_t)8 * 32 * 512);
    // 3. self attention (MFMA) -> saH
    attn_mfma<false><<<dim3(16, 8, 2), blk, 0, stream>>>(qkv_b, qkv_b + 256, vst, saH, nullptr, nullptr, 512, 768, 768, 512, 512);
    // 4. sa proj + bias + residual(query) -> tmp   [MFMA]
    gemm_mfma<1, 0, true, 0><<<dim3(16, 4), blk, 0, stream>>>(saH, sa_proj_w, sa_proj_b, query, tmp, nullptr, 1024, 256, 256);
    // 5. LN(norm3) -> x1
    ln_f32<<<dim3(256), blk, 0, stream>>>(tmp, norm3_g, norm3_b, x1);
    // 6. qc (bf16) = x1 @ q_w.T   [MFMA]
    gemm_mfma<0, 0, false, 1><<<dim3(16, 4), blk, 0, stream>>>(x1, q_w, nullptr, nullptr, nullptr, qc_b, 1024, 256, 256);
    // 7-10. per-batch
    for (int b = 0; b < 2; ++b) {
        const float* keyb = key + (size_t)b * 8192 * 256;
        const float* valb = value + (size_t)b * 8192 * 256;
        const u16* qcb = qc_b + (size_t)b * 512 * 256;
        gemm_mfma<0, 0, false, 1><<<dim3(128, 4), blk, 0, stream>>>(keyb, k_w, nullptr, nullptr, nullptr, kc_b, 8192, 256, 256);
        gemm_mfma<0, 0, false, 1><<<dim3(128, 4), blk, 0, stream>>>(valb, v_w, nullptr, nullptr, nullptr, vc_b, 8192, 256, 256);
        transpose_bf<<<dim3(128, 8, 1), blk, 0, stream>>>(vc_b, vt_b, 256, 8192, 0, 0);
        attn_mfma<true><<<dim3(16, 8, NSPLIT), blk, 0, stream>>>(qcb, kc_b, vt_b, po, pm, ps, 8192, 256, 256, 8192, 512);
        attn_combine<<<dim3(512), blk, 0, stream>>>(po, pm, ps, caH + (size_t)b * 512 * 256, 512, NSPLIT);
        smask_mfma<4><<<dim3(32, 16), blk, 0, stream>>>(qcb, kc_b, l1_w, l1_b, l2_w, l2_b,
                                                        outm + (size_t)b * 512 * 8192);
    }
    // 11. ca proj + bias + residual(x1) -> tmp   [MFMA]
    gemm_mfma<1, 0, true, 0><<<dim3(16, 4), blk, 0, stream>>>(caH, ca_proj_w, ca_proj_b, x1, tmp, nullptr, 1024, 256, 256);
    // 12. LN(ln1) -> x2
    ln_f32<<<dim3(256), blk, 0, stream>>>(tmp, ln1_g, ln1_b, x2);
    // 13. fc1 + bias + GELU -> hb   [MFMA]
    gemm_mfma<0, 1, true, 0><<<dim3(16, 16), blk, 0, stream>>>(x2, fc1_w, fc1_b, nullptr, hb, nullptr, 1024, 1024, 256);
    // 14. fc2 + bias + residual(x2) -> tmp   [MFMA, K=1024]
    gemm_mfma<1, 0, true, 0><<<dim3(16, 4), blk, 0, stream>>>(hb, fc2_w, fc2_b, x2, tmp, nullptr, 1024, 256, 1024);
    // 15. LN(ln2) -> outx
    ln_f32<<<dim3(256), blk, 0, stream>>>(tmp, ln2_g, ln2_b, outx);
}

// Round 24
// 300.245 us; speedup vs baseline: 1.1819x; 1.1819x over previous
//
#include <hip/hip_runtime.h>
#include <hip/hip_bf16.h>

#define BB 2
#define NN 512
#define LL 8192
#define CC 256
#define HH 8
#define DD 32
#define SCALE 0.17677669529663687f

typedef unsigned short u16;
typedef unsigned int u32;
typedef __attribute__((ext_vector_type(8))) short bf16x8;
typedef __attribute__((ext_vector_type(4))) float f32x4;

__device__ __forceinline__ float bf2f(u16 v) { return __uint_as_float(((u32)v) << 16); }
__device__ __forceinline__ u16 f2bf(float f) {
    u32 u = __float_as_uint(f);
    return (u16)((u + 0x7fffu + ((u >> 16) & 1u)) >> 16);
}
__device__ __forceinline__ bf16x8 ld8(const u16* p) { return *(const bf16x8*)p; }
__device__ __forceinline__ uint2 pack4(float4 v) {
    uint2 p;
    p.x = (u32)f2bf(v.x) | ((u32)f2bf(v.y) << 16);
    p.y = (u32)f2bf(v.z) | ((u32)f2bf(v.w) << 16);
    return p;
}

__global__ void sentinel(float* out, float val) {
    if (threadIdx.x == 0) out[0] = val;
}

// ---------------------------------------------------------------------------
// LDS-staged MFMA GEMM: C[M,N] = A[M,K] @ W[N,K]^T (+bias)(+res)(+gelu).
// 64x64 tile, 4 waves (wave = 16 rows x 64 cols). Staging: coalesced float4
// global loads, converted to bf16 ONCE at staging. LDS rows padded to 40 u16
// (80 B = 5x16B: b128-aligned fragments; bank stride 20 dw => 2-way = free).
// Fragment/epilogue mapping identical to r22-proven gemm_mfma.
// OUT: 0 f32, 1 bf16, 2 both.
// ---------------------------------------------------------------------------
template <int RES, int ACT, bool HAS_BIAS, int OUT>
__global__ __launch_bounds__(256) void gemm_ml(
    const float* __restrict__ A, const float* __restrict__ W,
    const float* __restrict__ bias, const float* __restrict__ res,
    float* __restrict__ Cf, u16* __restrict__ Cb, int M, int N, int K)
{
    __shared__ alignas(16) u16 As[64][40], Ws[64][40];
    int t = threadIdx.x;
    int lane = t & 63, wave = t >> 6;
    int lr = lane & 15, lg = lane >> 4;
    int m0 = blockIdx.x * 64, n0 = blockIdx.y * 64;
    int srow = t >> 3, sc4 = (t & 7) * 4;       // staging: row 0..31, col 0..28
    f32x4 acc[4] = {};
    for (int k0 = 0; k0 < K; k0 += 32) {
        *(uint2*)&As[srow][sc4]      = pack4(*(const float4*)&A[(size_t)(m0 + srow) * K + k0 + sc4]);
        *(uint2*)&As[srow + 32][sc4] = pack4(*(const float4*)&A[(size_t)(m0 + 32 + srow) * K + k0 + sc4]);
        *(uint2*)&Ws[srow][sc4]      = pack4(*(const float4*)&W[(size_t)(n0 + srow) * K + k0 + sc4]);
        *(uint2*)&Ws[srow + 32][sc4] = pack4(*(const float4*)&W[(size_t)(n0 + 32 + srow) * K + k0 + sc4]);
        __syncthreads();
        bf16x8 af = ld8(&As[wave * 16 + lr][lg * 8]);
#pragma unroll
        for (int nt = 0; nt < 4; ++nt) {
            bf16x8 wf = ld8(&Ws[nt * 16 + lr][lg * 8]);
            acc[nt] = __builtin_amdgcn_mfma_f32_16x16x32_bf16(af, wf, acc[nt], 0, 0, 0);
        }
        __syncthreads();
    }
#pragma unroll
    for (int nt = 0; nt < 4; ++nt) {
        int col = n0 + nt * 16 + lr;
        float bv = HAS_BIAS ? bias[col] : 0.f;
#pragma unroll
        for (int r = 0; r < 4; ++r) {
            int row = m0 + wave * 16 + lg * 4 + r;
            float v = acc[nt][r] + bv;
            if (RES) v += res[(size_t)row * N + col];
            if (ACT) v = 0.5f * v * (1.f + erff(v * 0.70710678118f));
            if (OUT == 0 || OUT == 2) Cf[(size_t)row * N + col] = v;
            if (OUT == 1 || OUT == 2) Cb[(size_t)row * N + col] = f2bf(v);
        }
    }
}

// ---------------------------------------------------------------------------
// bf16 head-transpose (r20 proven).
// ---------------------------------------------------------------------------
__global__ __launch_bounds__(256) void transpose_bf(
    const u16* __restrict__ in, u16* __restrict__ out,
    int rowStride, int vtL, size_t bStrideIn, size_t bStrideOut)
{
    __shared__ alignas(16) u16 tl[64][33];
    int r0 = blockIdx.x * 64;
    int h = blockIdx.y, b = blockIdx.z;
    const u16* ip = in + (size_t)b * bStrideIn + h * DD;
    for (int i = threadIdx.x; i < 64 * 32; i += 256) {
        int r = i >> 5, d = i & 31;
        tl[r][d] = ip[(size_t)(r0 + r) * rowStride + d];
    }
    __syncthreads();
    u16* op = out + (size_t)b * bStrideOut + (size_t)h * DD * vtL + r0;
    for (int i = threadIdx.x; i < 64 * 32; i += 256) {
        int r = i & 63, d = i >> 6;
        op[(size_t)d * vtL + r] = tl[r][d];
    }
}

// ---------------------------------------------------------------------------
// MFMA flash attention (r20 proven).
// ---------------------------------------------------------------------------
template <bool SPLIT>
__global__ __launch_bounds__(256) void attn_mfma(
    const u16* __restrict__ qp, const u16* __restrict__ kp,
    const u16* __restrict__ vt, float* __restrict__ outp,
    float* __restrict__ pm, float* __restrict__ ps_,
    int Lk, int qStride, int kStride, int vtL, int Nq)
{
    __shared__ alignas(16) u16 plds[4][32][48];
    __shared__ alignas(16) float comb[4][32][34];
    int lane = threadIdx.x & 63, wave = threadIdx.x >> 6;
    int lr = lane & 15, lg = lane >> 4;
    int h = blockIdx.y, n0 = blockIdx.x * 32, z = blockIdx.z;
    size_t qoff = 0, koff = 0, voff = 0;
    int lbeg, lend;
    if (SPLIT) {
        int chunk = Lk / (gridDim.z * 4);
        lbeg = z * (Lk / gridDim.z) + wave * chunk;
        lend = lbeg + chunk;
    } else {
        int chunk = Lk / 4;
        lbeg = wave * chunk;
        lend = lbeg + chunk;
        qoff = (size_t)z * Nq * qStride;
        koff = (size_t)z * Lk * kStride;
        voff = (size_t)z * HH * DD * vtL;
    }

    bf16x8 bq[2];
#pragma unroll
    for (int nh = 0; nh < 2; ++nh)
        bq[nh] = ld8(qp + qoff + (size_t)(n0 + nh * 16 + lr) * qStride + h * DD + lg * 8);

    f32x4 o[2][2] = {};
    float m = -1e30f, s = 0.f;
    float m2 = -1e30f, s2 = 0.f;
    const u16* kb = kp + koff + h * DD + lg * 8;
    const u16* vb0 = vt + voff + (size_t)h * DD * vtL;

    for (int l0 = lbeg; l0 < lend; l0 += 32) {
        bf16x8 ka[2];
#pragma unroll
        for (int lt = 0; lt < 2; ++lt)
            ka[lt] = ld8(kb + (size_t)(l0 + lt * 16 + lr) * kStride);
        f32x4 st[2][2];
#pragma unroll
        for (int lt = 0; lt < 2; ++lt)
#pragma unroll
            for (int nh = 0; nh < 2; ++nh) {
                f32x4 zz = {0.f, 0.f, 0.f, 0.f};
                st[lt][nh] = __builtin_amdgcn_mfma_f32_16x16x32_bf16(ka[lt], bq[nh], zz, 0, 0, 0);
            }
        float aq[2];
#pragma unroll
        for (int nh = 0; nh < 2; ++nh) {
            float mprev = (nh == 0) ? m : m2;
            float sprev = (nh == 0) ? s : s2;
            float mx = -1e30f;
#pragma unroll
            for (int lt = 0; lt < 2; ++lt)
#pragma unroll
                for (int r = 0; r < 4; ++r) {
                    float v = st[lt][nh][r] * SCALE;
                    st[lt][nh][r] = v;
                    mx = fmaxf(mx, v);
                }
            mx = fmaxf(mx, __shfl_xor(mx, 16));
            mx = fmaxf(mx, __shfl_xor(mx, 32));
            float mn = fmaxf(mprev, mx);
            float alpha = __expf(mprev - mn);
            float rs = 0.f;
#pragma unroll
            for (int lt = 0; lt < 2; ++lt) {
                u16 pk[4];
#pragma unroll
                for (int r = 0; r < 4; ++r) {
                    float p = __expf(st[lt][nh][r] - mn);
                    rs += p;
                    pk[r] = f2bf(p);
                }
                uint2 pv;
                pv.x = (u32)pk[0] | ((u32)pk[1] << 16);
                pv.y = (u32)pk[2] | ((u32)pk[3] << 16);
                *(uint2*)&plds[wave][nh * 16 + lr][lt * 16 + lg * 4] = pv;
            }
            rs += __shfl_xor(rs, 16);
            rs += __shfl_xor(rs, 32);
            if (nh == 0) { s = sprev * alpha + rs; m = mn; }
            else         { s2 = sprev * alpha + rs; m2 = mn; }
            aq[nh] = alpha;
        }
#pragma unroll
        for (int qt = 0; qt < 2; ++qt)
#pragma unroll
            for (int r = 0; r < 4; ++r) {
                float al = __shfl(aq[qt], (lg << 2) + r);
                o[qt][0][r] *= al;
                o[qt][1][r] *= al;
            }
        asm volatile("" ::: "memory");
        bf16x8 pa[2], vv[2];
#pragma unroll
        for (int qt = 0; qt < 2; ++qt)
            pa[qt] = ld8(&plds[wave][qt * 16 + lr][lg * 8]);
        asm volatile("" ::: "memory");
#pragma unroll
        for (int dt = 0; dt < 2; ++dt)
            vv[dt] = ld8(vb0 + (size_t)(dt * 16 + lr) * vtL + l0 + lg * 8);
#pragma unroll
        for (int qt = 0; qt < 2; ++qt)
#pragma unroll
            for (int dt = 0; dt < 2; ++dt)
                o[qt][dt] = __builtin_amdgcn_mfma_f32_16x16x32_bf16(pa[qt], vv[dt], o[qt][dt], 0, 0, 0);
    }

#pragma unroll
    for (int qt = 0; qt < 2; ++qt)
#pragma unroll
        for (int dt = 0; dt < 2; ++dt)
#pragma unroll
            for (int r = 0; r < 4; ++r)
                comb[wave][qt * 16 + lg * 4 + r][dt * 16 + lr] = o[qt][dt][r];
    if (lg == 0) {
        comb[wave][lr][32] = m;       comb[wave][lr][33] = s;
        comb[wave][16 + lr][32] = m2; comb[wave][16 + lr][33] = s2;
    }
    __syncthreads();
    for (int idx = threadIdx.x; idx < 1024; idx += 256) {
        int q2 = idx >> 5, d = idx & 31;
        float mm = -1e30f;
#pragma unroll
        for (int w = 0; w < 4; ++w) mm = fmaxf(mm, comb[w][q2][32]);
        float num = 0.f, den = 0.f;
#pragma unroll
        for (int w = 0; w < 4; ++w) {
            float e = __expf(comb[w][q2][32] - mm);
            num += e * comb[w][q2][d];
            den += e * comb[w][q2][33];
        }
        int n = n0 + q2;
        if (SPLIT) {
            outp[((size_t)z * Nq + n) * CC + h * DD + d] = num;
            if (d == 0) {
                pm[((size_t)z * Nq + n) * HH + h] = mm;
                ps_[((size_t)z * Nq + n) * HH + h] = den;
            }
        } else {
            outp[((size_t)z * Nq + n) * CC + h * DD + d] = num / den;
        }
    }
}

// ---------------------------------------------------------------------------
// Combine flash partials (r19/r20 proven).
// ---------------------------------------------------------------------------
__global__ __launch_bounds__(256) void attn_combine(
    const float* __restrict__ po, const float* __restrict__ pm,
    const float* __restrict__ ps, float* __restrict__ out,
    int Nq, int nsplit)
{
    int idx = blockIdx.x * 256 + threadIdx.x;
    if (idx >= Nq * CC) return;
    int n = idx >> 8, cd = idx & 255;
    int h = cd >> 5;
    float mm = -1e30f;
    for (int zz = 0; zz < nsplit; ++zz)
        mm = fmaxf(mm, pm[((size_t)zz * Nq + n) * HH + h]);
    float num = 0.f, den = 0.f;
    for (int zz = 0; zz < nsplit; ++zz) {
        float e = __expf(pm[((size_t)zz * Nq + n) * HH + h] - mm);
        num += e * po[((size_t)zz * Nq + n) * CC + cd];
        den += e * ps[((size_t)zz * Nq + n) * HH + h];
    }
    out[(size_t)n * CC + cd] = num / den;
}

// ---------------------------------------------------------------------------
// MFMA mask (r21 proven).
// ---------------------------------------------------------------------------
template <int NL>
__global__ __launch_bounds__(256) void smask_mfma(
    const u16* __restrict__ qcb, const u16* __restrict__ kcb,
    const float* __restrict__ w1, const float* __restrict__ b1,
    const float* __restrict__ w2, const float* __restrict__ b2,
    float* __restrict__ mout)
{
    int lane = threadIdx.x & 63, wave = threadIdx.x >> 6;
    int lr = lane & 15, lg = lane >> 4;
    int n0 = blockIdx.y * 32;
    bf16x8 bq[8][2];
#pragma unroll
    for (int h = 0; h < 8; ++h)
#pragma unroll
        for (int nh = 0; nh < 2; ++nh)
            bq[h][nh] = ld8(qcb + (size_t)(n0 + nh * 16 + lr) * CC + h * DD + lg * 8);
    float b2v = b2[0];
    for (int it = 0; it < NL; ++it) {
        int l0 = (blockIdx.x * NL + it) * 64 + wave * 16;
        bf16x8 ka[8];
#pragma unroll
        for (int h = 0; h < 8; ++h)
            ka[h] = ld8(kcb + (size_t)(l0 + lr) * CC + h * DD + lg * 8);
#pragma unroll
        for (int nh = 0; nh < 2; ++nh) {
            f32x4 st[8];
#pragma unroll
            for (int h = 0; h < 8; ++h) {
                f32x4 zz = {0.f, 0.f, 0.f, 0.f};
                st[h] = __builtin_amdgcn_mfma_f32_16x16x32_bf16(ka[h], bq[h][nh], zz, 0, 0, 0);
            }
            float4 res;
            float* rp = &res.x;
#pragma unroll
            for (int r = 0; r < 4; ++r) {
                float s[8];
#pragma unroll
                for (int i = 0; i < 8; ++i) s[i] = st[i][r] * SCALE;
                float acc2 = b2v;
#pragma unroll
                for (int o = 0; o < 8; ++o) {
                    float f = b1[o];
#pragma unroll
                    for (int i = 0; i < 8; ++i) f += s[i] * w1[o * 8 + i];
                    f = fmaxf(f, 0.f);
                    acc2 += f * w2[o];
                }
                rp[r] = fmaxf(acc2, 0.f);
            }
            *(float4*)&mout[(size_t)(n0 + nh * 16 + lr) * LL + l0 + lg * 4] = res;
        }
    }
}

// ---------------------------------------------------------------------------
// f32 LayerNorm over C=256 (r17 proven).
// ---------------------------------------------------------------------------
__global__ __launch_bounds__(256) void ln_f32(
    const float* __restrict__ a, const float* __restrict__ g,
    const float* __restrict__ be, float* __restrict__ out)
{
    int lane = threadIdx.x & 63, wave = threadIdx.x >> 6;
    int row = blockIdx.x * 4 + wave;
    float4 v = *(const float4*)(a + (size_t)row * CC + lane * 4);
    float sum = v.x + v.y + v.z + v.w;
    float sq = v.x * v.x + v.y * v.y + v.z * v.z + v.w * v.w;
#pragma unroll
    for (int mk = 1; mk < 64; mk <<= 1) {
        sum += __shfl_xor(sum, mk);
        sq += __shfl_xor(sq, mk);
    }
    float mean = sum * (1.f / 256.f);
    float var = sq * (1.f / 256.f) - mean * mean;
    float rstd = rsqrtf(var + 1e-5f);
    int c = lane * 4;
    float4 ov;
    ov.x = (v.x - mean) * rstd * g[c + 0] + be[c + 0];
    ov.y = (v.y - mean) * rstd * g[c + 1] + be[c + 1];
    ov.z = (v.z - mean) * rstd * g[c + 2] + be[c + 2];
    ov.w = (v.w - mean) * rstd * g[c + 3] + be[c + 3];
    *(float4*)(out + (size_t)row * CC + c) = ov;
}

// ---------------------------------------------------------------------------
extern "C" void kernel_launch(void* const* d_in, const int* in_sizes, int n_in,
                              void* d_out, int out_size, void* d_ws, size_t ws_size,
                              hipStream_t stream)
{
    (void)in_sizes; (void)n_in; (void)out_size;
    float* outx = (float*)d_out;
    float* outm = outx + (size_t)BB * NN * CC;

    const float* query     = (const float*)d_in[0];
    const float* key       = (const float*)d_in[1];
    const float* value     = (const float*)d_in[2];
    const float* sa_qkv_w  = (const float*)d_in[3];
    const float* sa_proj_w = (const float*)d_in[4];
    const float* sa_proj_b = (const float*)d_in[5];
    const float* norm3_g   = (const float*)d_in[6];
    const float* norm3_b   = (const float*)d_in[7];
    const float* q_w       = (const float*)d_in[8];
    const float* k_w       = (const float*)d_in[9];
    const float* v_w       = (const float*)d_in[10];
    const float* ca_proj_w = (const float*)d_in[11];
    const float* ca_proj_b = (const float*)d_in[12];
    const float* l1_w      = (const float*)d_in[13];
    const float* l1_b      = (const float*)d_in[14];
    const float* l2_w      = (const float*)d_in[15];
    const float* l2_b      = (const float*)d_in[16];
    const float* ln1_g     = (const float*)d_in[17];
    const float* ln1_b     = (const float*)d_in[18];
    const float* ln2_g     = (const float*)d_in[19];
    const float* ln2_b     = (const float*)d_in[20];
    const float* fc1_w     = (const float*)d_in[21];
    const float* fc1_b     = (const float*)d_in[22];
    const float* fc2_w     = (const float*)d_in[23];
    const float* fc2_b     = (const float*)d_in[24];

    const int NSPLIT = 8;

    char* w0 = (char*)d_ws;
    char* unionA = w0;                 w0 += (size_t)16 * 1024 * 1024;
    float* saH = (float*)w0;           w0 += (size_t)1024 * 256 * 4;
    float* x1  = (float*)w0;           w0 += (size_t)1024 * 256 * 4;
    float* x2  = (float*)w0;           w0 += (size_t)1024 * 256 * 4;
    float* tmp = (float*)w0;           w0 += (size_t)1024 * 256 * 4;
    float* caH = (float*)w0;           w0 += (size_t)1024 * 256 * 4;
    u16*   qc_b = (u16*)w0;            w0 += (size_t)1024 * 256 * 2;
    float* po  = (float*)w0;           w0 += (size_t)NSPLIT * 512 * 256 * 4;
    float* pm  = (float*)w0;           w0 += (size_t)NSPLIT * 512 * 8 * 4;
    float* ps  = (float*)w0;           w0 += (size_t)NSPLIT * 512 * 8 * 4;
    size_t need = (size_t)(w0 - (char*)d_ws);
    u16* qkv_b = (u16*)unionA;                                   // 1024 x 768
    u16* vst   = (u16*)(unionA + (size_t)1024 * 768 * 2);        // (B,H,D,512)
    u16* kc_b  = (u16*)unionA;                                   // 8192 x 256
    u16* vc_b  = (u16*)(unionA + (size_t)8192 * 256 * 2);        // 8192 x 256
    u16* vt_b  = (u16*)(unionA + (size_t)2 * 8192 * 256 * 2);    // (H,D,8192)
    float* hb  = (float*)unionA;                                 // 1024 x 1024

    if (ws_size < need) {
        sentinel<<<dim3(1), dim3(64), 0, stream>>>(outx, 1000.f + (float)(ws_size >> 20));
        return;
    }

    dim3 blk(256);

    // 1. qkv (bf16) = query @ sa_qkv_w.T
    gemm_ml<0, 0, false, 1><<<dim3(16, 12), blk, 0, stream>>>(query, sa_qkv_w, nullptr, nullptr, nullptr, qkv_b, 1024, 768, 256);
    // 2. self V^T
    transpose_bf<<<dim3(8, 8, 2), blk, 0, stream>>>(qkv_b + 512, vst, 768, 512, (size_t)512 * 768, (size_t)8 * 32 * 512);
    // 3. self attention (MFMA) -> saH
    attn_mfma<false><<<dim3(16, 8, 2), blk, 0, stream>>>(qkv_b, qkv_b + 256, vst, saH, nullptr, nullptr, 512, 768, 768, 512, 512);
    // 4. sa proj + bias + residual(query) -> tmp
    gemm_ml<1, 0, true, 0><<<dim3(16, 4), blk, 0, stream>>>(saH, sa_proj_w, sa_proj_b, query, tmp, nullptr, 1024, 256, 256);
    // 5. LN(norm3) -> x1
    ln_f32<<<dim3(256), blk, 0, stream>>>(tmp, norm3_g, norm3_b, x1);
    // 6. qc (bf16) = x1 @ q_w.T
    gemm_ml<0, 0, false, 1><<<dim3(16, 4), blk, 0, stream>>>(x1, q_w, nullptr, nullptr, nullptr, qc_b, 1024, 256, 256);
    // 7-10. per-batch
    for (int b = 0; b < 2; ++b) {
        const float* keyb = key + (size_t)b * 8192 * 256;
        const float* valb = value + (size_t)b * 8192 * 256;
        const u16* qcb = qc_b + (size_t)b * 512 * 256;
        gemm_ml<0, 0, false, 1><<<dim3(128, 4), blk, 0, stream>>>(keyb, k_w, nullptr, nullptr, nullptr, kc_b, 8192, 256, 256);
        gemm_ml<0, 0, false, 1><<<dim3(128, 4), blk, 0, stream>>>(valb, v_w, nullptr, nullptr, nullptr, vc_b, 8192, 256, 256);
        transpose_bf<<<dim3(128, 8, 1), blk, 0, stream>>>(vc_b, vt_b, 256, 8192, 0, 0);
        attn_mfma<true><<<dim3(16, 8, NSPLIT), blk, 0, stream>>>(qcb, kc_b, vt_b, po, pm, ps, 8192, 256, 256, 8192, 512);
        attn_combine<<<dim3(512), blk, 0, stream>>>(po, pm, ps, caH + (size_t)b * 512 * 256, 512, NSPLIT);
        smask_mfma<4><<<dim3(32, 16), blk, 0, stream>>>(qcb, kc_b, l1_w, l1_b, l2_w, l2_b,
                                                        outm + (size_t)b * 512 * 8192);
    }
    // 11. ca proj + bias + residual(x1) -> tmp
    gemm_ml<1, 0, true, 0><<<dim3(16, 4), blk, 0, stream>>>(caH, ca_proj_w, ca_proj_b, x1, tmp, nullptr, 1024, 256, 256);
    // 12. LN(ln1) -> x2
    ln_f32<<<dim3(256), blk, 0, stream>>>(tmp, ln1_g, ln1_b, x2);
    // 13. fc1 + bias + GELU -> hb
    gemm_ml<0, 1, true, 0><<<dim3(16, 16), blk, 0, stream>>>(x2, fc1_w, fc1_b, nullptr, hb, nullptr, 1024, 1024, 256);
    // 14. fc2 + bias + residual(x2) -> tmp (K=1024)
    gemm_ml<1, 0, true, 0><<<dim3(16, 4), blk, 0, stream>>>(hb, fc2_w, fc2_b, x2, tmp, nullptr, 1024, 256, 1024);
    // 15. LN(ln2) -> outx
    ln_f32<<<dim3(256), blk, 0, stream>>>(tmp, ln2_g, ln2_b, outx);
}

// Round 25
// 216.460 us; speedup vs baseline: 1.6393x; 1.3871x over previous
//
#include <hip/hip_runtime.h>
#include <hip/hip_bf16.h>

#define BB 2
#define NN 512
#define LL 8192
#define CC 256
#define HH 8
#define DD 32
#define SCALE 0.17677669529663687f

typedef unsigned short u16;
typedef unsigned int u32;
typedef __attribute__((ext_vector_type(8))) short bf16x8;
typedef __attribute__((ext_vector_type(4))) float f32x4;

__device__ __forceinline__ float bf2f(u16 v) { return __uint_as_float(((u32)v) << 16); }
__device__ __forceinline__ u16 f2bf(float f) {
    u32 u = __float_as_uint(f);
    return (u16)((u + 0x7fffu + ((u >> 16) & 1u)) >> 16);
}
__device__ __forceinline__ bf16x8 ld8(const u16* p) { return *(const bf16x8*)p; }
__device__ __forceinline__ uint2 pack4(float4 v) {
    uint2 p;
    p.x = (u32)f2bf(v.x) | ((u32)f2bf(v.y) << 16);
    p.y = (u32)f2bf(v.z) | ((u32)f2bf(v.w) << 16);
    return p;
}

__global__ void sentinel(float* out, float val) {
    if (threadIdx.x == 0) out[0] = val;
}

// ---------------------------------------------------------------------------
// LDS-staged MFMA GEMM with 1-deep software prefetch:
//   prefetch tile0 -> loop { LDS-write(prefetched); barrier; issue prefetch
//   k+1; ds_read + MFMA (waits only lgkmcnt, global loads stay in flight);
//   barrier }  — per-tile cost ~max(load, compute) instead of load+compute.
// 64x64 tile, 4 waves; LDS rows padded to 40 u16. r24-proven mapping.
// OUT: 0 f32, 1 bf16, 2 both.
// ---------------------------------------------------------------------------
template <int RES, int ACT, bool HAS_BIAS, int OUT>
__global__ __launch_bounds__(256) void gemm_ml(
    const float* __restrict__ A, const float* __restrict__ W,
    const float* __restrict__ bias, const float* __restrict__ res,
    float* __restrict__ Cf, u16* __restrict__ Cb, int M, int N, int K)
{
    __shared__ alignas(16) u16 As[64][40], Ws[64][40];
    int t = threadIdx.x;
    int lane = t & 63, wave = t >> 6;
    int lr = lane & 15, lg = lane >> 4;
    int m0 = blockIdx.x * 64, n0 = blockIdx.y * 64;
    int srow = t >> 3, sc4 = (t & 7) * 4;
    const float* pa0 = &A[(size_t)(m0 + srow) * K + sc4];
    const float* pa1 = &A[(size_t)(m0 + 32 + srow) * K + sc4];
    const float* pw0 = &W[(size_t)(n0 + srow) * K + sc4];
    const float* pw1 = &W[(size_t)(n0 + 32 + srow) * K + sc4];
    float4 ra0 = *(const float4*)(pa0);
    float4 ra1 = *(const float4*)(pa1);
    float4 rw0 = *(const float4*)(pw0);
    float4 rw1 = *(const float4*)(pw1);
    f32x4 acc[4] = {};
    for (int k0 = 0; k0 < K; k0 += 32) {
        *(uint2*)&As[srow][sc4]      = pack4(ra0);
        *(uint2*)&As[srow + 32][sc4] = pack4(ra1);
        *(uint2*)&Ws[srow][sc4]      = pack4(rw0);
        *(uint2*)&Ws[srow + 32][sc4] = pack4(rw1);
        __syncthreads();
        if (k0 + 32 < K) {
            ra0 = *(const float4*)(pa0 + k0 + 32);
            ra1 = *(const float4*)(pa1 + k0 + 32);
            rw0 = *(const float4*)(pw0 + k0 + 32);
            rw1 = *(const float4*)(pw1 + k0 + 32);
        }
        bf16x8 af = ld8(&As[wave * 16 + lr][lg * 8]);
#pragma unroll
        for (int nt = 0; nt < 4; ++nt) {
            bf16x8 wf = ld8(&Ws[nt * 16 + lr][lg * 8]);
            acc[nt] = __builtin_amdgcn_mfma_f32_16x16x32_bf16(af, wf, acc[nt], 0, 0, 0);
        }
        __syncthreads();
    }
#pragma unroll
    for (int nt = 0; nt < 4; ++nt) {
        int col = n0 + nt * 16 + lr;
        float bv = HAS_BIAS ? bias[col] : 0.f;
#pragma unroll
        for (int r = 0; r < 4; ++r) {
            int row = m0 + wave * 16 + lg * 4 + r;
            float v = acc[nt][r] + bv;
            if (RES) v += res[(size_t)row * N + col];
            if (ACT) v = 0.5f * v * (1.f + erff(v * 0.70710678118f));
            if (OUT == 0 || OUT == 2) Cf[(size_t)row * N + col] = v;
            if (OUT == 1 || OUT == 2) Cb[(size_t)row * N + col] = f2bf(v);
        }
    }
}

// ---------------------------------------------------------------------------
// bf16 head-transpose (r20 proven).
// ---------------------------------------------------------------------------
__global__ __launch_bounds__(256) void transpose_bf(
    const u16* __restrict__ in, u16* __restrict__ out,
    int rowStride, int vtL, size_t bStrideIn, size_t bStrideOut)
{
    __shared__ alignas(16) u16 tl[64][33];
    int r0 = blockIdx.x * 64;
    int h = blockIdx.y, b = blockIdx.z;
    const u16* ip = in + (size_t)b * bStrideIn + h * DD;
    for (int i = threadIdx.x; i < 64 * 32; i += 256) {
        int r = i >> 5, d = i & 31;
        tl[r][d] = ip[(size_t)(r0 + r) * rowStride + d];
    }
    __syncthreads();
    u16* op = out + (size_t)b * bStrideOut + (size_t)h * DD * vtL + r0;
    for (int i = threadIdx.x; i < 64 * 32; i += 256) {
        int r = i & 63, d = i >> 6;
        op[(size_t)d * vtL + r] = tl[r][d];
    }
}

// ---------------------------------------------------------------------------
// MFMA flash attention (r20 proven).
// ---------------------------------------------------------------------------
template <bool SPLIT>
__global__ __launch_bounds__(256) void attn_mfma(
    const u16* __restrict__ qp, const u16* __restrict__ kp,
    const u16* __restrict__ vt, float* __restrict__ outp,
    float* __restrict__ pm, float* __restrict__ ps_,
    int Lk, int qStride, int kStride, int vtL, int Nq)
{
    __shared__ alignas(16) u16 plds[4][32][48];
    __shared__ alignas(16) float comb[4][32][34];
    int lane = threadIdx.x & 63, wave = threadIdx.x >> 6;
    int lr = lane & 15, lg = lane >> 4;
    int h = blockIdx.y, n0 = blockIdx.x * 32, z = blockIdx.z;
    size_t qoff = 0, koff = 0, voff = 0;
    int lbeg, lend;
    if (SPLIT) {
        int chunk = Lk / (gridDim.z * 4);
        lbeg = z * (Lk / gridDim.z) + wave * chunk;
        lend = lbeg + chunk;
    } else {
        int chunk = Lk / 4;
        lbeg = wave * chunk;
        lend = lbeg + chunk;
        qoff = (size_t)z * Nq * qStride;
        koff = (size_t)z * Lk * kStride;
        voff = (size_t)z * HH * DD * vtL;
    }

    bf16x8 bq[2];
#pragma unroll
    for (int nh = 0; nh < 2; ++nh)
        bq[nh] = ld8(qp + qoff + (size_t)(n0 + nh * 16 + lr) * qStride + h * DD + lg * 8);

    f32x4 o[2][2] = {};
    float m = -1e30f, s = 0.f;
    float m2 = -1e30f, s2 = 0.f;
    const u16* kb = kp + koff + h * DD + lg * 8;
    const u16* vb0 = vt + voff + (size_t)h * DD * vtL;

    for (int l0 = lbeg; l0 < lend; l0 += 32) {
        bf16x8 ka[2];
#pragma unroll
        for (int lt = 0; lt < 2; ++lt)
            ka[lt] = ld8(kb + (size_t)(l0 + lt * 16 + lr) * kStride);
        f32x4 st[2][2];
#pragma unroll
        for (int lt = 0; lt < 2; ++lt)
#pragma unroll
            for (int nh = 0; nh < 2; ++nh) {
                f32x4 zz = {0.f, 0.f, 0.f, 0.f};
                st[lt][nh] = __builtin_amdgcn_mfma_f32_16x16x32_bf16(ka[lt], bq[nh], zz, 0, 0, 0);
            }
        float aq[2];
#pragma unroll
        for (int nh = 0; nh < 2; ++nh) {
            float mprev = (nh == 0) ? m : m2;
            float sprev = (nh == 0) ? s : s2;
            float mx = -1e30f;
#pragma unroll
            for (int lt = 0; lt < 2; ++lt)
#pragma unroll
                for (int r = 0; r < 4; ++r) {
                    float v = st[lt][nh][r] * SCALE;
                    st[lt][nh][r] = v;
                    mx = fmaxf(mx, v);
                }
            mx = fmaxf(mx, __shfl_xor(mx, 16));
            mx = fmaxf(mx, __shfl_xor(mx, 32));
            float mn = fmaxf(mprev, mx);
            float alpha = __expf(mprev - mn);
            float rs = 0.f;
#pragma unroll
            for (int lt = 0; lt < 2; ++lt) {
                u16 pk[4];
#pragma unroll
                for (int r = 0; r < 4; ++r) {
                    float p = __expf(st[lt][nh][r] - mn);
                    rs += p;
                    pk[r] = f2bf(p);
                }
                uint2 pv;
                pv.x = (u32)pk[0] | ((u32)pk[1] << 16);
                pv.y = (u32)pk[2] | ((u32)pk[3] << 16);
                *(uint2*)&plds[wave][nh * 16 + lr][lt * 16 + lg * 4] = pv;
            }
            rs += __shfl_xor(rs, 16);
            rs += __shfl_xor(rs, 32);
            if (nh == 0) { s = sprev * alpha + rs; m = mn; }
            else         { s2 = sprev * alpha + rs; m2 = mn; }
            aq[nh] = alpha;
        }
#pragma unroll
        for (int qt = 0; qt < 2; ++qt)
#pragma unroll
            for (int r = 0; r < 4; ++r) {
                float al = __shfl(aq[qt], (lg << 2) + r);
                o[qt][0][r] *= al;
                o[qt][1][r] *= al;
            }
        asm volatile("" ::: "memory");
        bf16x8 pa[2], vv[2];
#pragma unroll
        for (int qt = 0; qt < 2; ++qt)
            pa[qt] = ld8(&plds[wave][qt * 16 + lr][lg * 8]);
        asm volatile("" ::: "memory");
#pragma unroll
        for (int dt = 0; dt < 2; ++dt)
            vv[dt] = ld8(vb0 + (size_t)(dt * 16 + lr) * vtL + l0 + lg * 8);
#pragma unroll
        for (int qt = 0; qt < 2; ++qt)
#pragma unroll
            for (int dt = 0; dt < 2; ++dt)
                o[qt][dt] = __builtin_amdgcn_mfma_f32_16x16x32_bf16(pa[qt], vv[dt], o[qt][dt], 0, 0, 0);
    }

#pragma unroll
    for (int qt = 0; qt < 2; ++qt)
#pragma unroll
        for (int dt = 0; dt < 2; ++dt)
#pragma unroll
            for (int r = 0; r < 4; ++r)
                comb[wave][qt * 16 + lg * 4 + r][dt * 16 + lr] = o[qt][dt][r];
    if (lg == 0) {
        comb[wave][lr][32] = m;       comb[wave][lr][33] = s;
        comb[wave][16 + lr][32] = m2; comb[wave][16 + lr][33] = s2;
    }
    __syncthreads();
    for (int idx = threadIdx.x; idx < 1024; idx += 256) {
        int q2 = idx >> 5, d = idx & 31;
        float mm = -1e30f;
#pragma unroll
        for (int w = 0; w < 4; ++w) mm = fmaxf(mm, comb[w][q2][32]);
        float num = 0.f, den = 0.f;
#pragma unroll
        for (int w = 0; w < 4; ++w) {
            float e = __expf(comb[w][q2][32] - mm);
            num += e * comb[w][q2][d];
            den += e * comb[w][q2][33];
        }
        int n = n0 + q2;
        if (SPLIT) {
            outp[((size_t)z * Nq + n) * CC + h * DD + d] = num;
            if (d == 0) {
                pm[((size_t)z * Nq + n) * HH + h] = mm;
                ps_[((size_t)z * Nq + n) * HH + h] = den;
            }
        } else {
            outp[((size_t)z * Nq + n) * CC + h * DD + d] = num / den;
        }
    }
}

// ---------------------------------------------------------------------------
// Combine flash partials (r19/r20 proven).
// ---------------------------------------------------------------------------
__global__ __launch_bounds__(256) void attn_combine(
    const float* __restrict__ po, const float* __restrict__ pm,
    const float* __restrict__ ps, float* __restrict__ out,
    int Nq, int nsplit)
{
    int idx = blockIdx.x * 256 + threadIdx.x;
    if (idx >= Nq * CC) return;
    int n = idx >> 8, cd = idx & 255;
    int h = cd >> 5;
    float mm = -1e30f;
    for (int zz = 0; zz < nsplit; ++zz)
        mm = fmaxf(mm, pm[((size_t)zz * Nq + n) * HH + h]);
    float num = 0.f, den = 0.f;
    for (int zz = 0; zz < nsplit; ++zz) {
        float e = __expf(pm[((size_t)zz * Nq + n) * HH + h] - mm);
        num += e * po[((size_t)zz * Nq + n) * CC + cd];
        den += e * ps[((size_t)zz * Nq + n) * HH + h];
    }
    out[(size_t)n * CC + cd] = num / den;
}

// ---------------------------------------------------------------------------
// MFMA mask (r21 proven).
// ---------------------------------------------------------------------------
template <int NL>
__global__ __launch_bounds__(256) void smask_mfma(
    const u16* __restrict__ qcb, const u16* __restrict__ kcb,
    const float* __restrict__ w1, const float* __restrict__ b1,
    const float* __restrict__ w2, const float* __restrict__ b2,
    float* __restrict__ mout)
{
    int lane = threadIdx.x & 63, wave = threadIdx.x >> 6;
    int lr = lane & 15, lg = lane >> 4;
    int n0 = blockIdx.y * 32;
    bf16x8 bq[8][2];
#pragma unroll
    for (int h = 0; h < 8; ++h)
#pragma unroll
        for (int nh = 0; nh < 2; ++nh)
            bq[h][nh] = ld8(qcb + (size_t)(n0 + nh * 16 + lr) * CC + h * DD + lg * 8);
    float b2v = b2[0];
    for (int it = 0; it < NL; ++it) {
        int l0 = (blockIdx.x * NL + it) * 64 + wave * 16;
        bf16x8 ka[8];
#pragma unroll
        for (int h = 0; h < 8; ++h)
            ka[h] = ld8(kcb + (size_t)(l0 + lr) * CC + h * DD + lg * 8);
#pragma unroll
        for (int nh = 0; nh < 2; ++nh) {
            f32x4 st[8];
#pragma unroll
            for (int h = 0; h < 8; ++h) {
                f32x4 zz = {0.f, 0.f, 0.f, 0.f};
                st[h] = __builtin_amdgcn_mfma_f32_16x16x32_bf16(ka[h], bq[h][nh], zz, 0, 0, 0);
            }
            float4 res;
            float* rp = &res.x;
#pragma unroll
            for (int r = 0; r < 4; ++r) {
                float s[8];
#pragma unroll
                for (int i = 0; i < 8; ++i) s[i] = st[i][r] * SCALE;
                float acc2 = b2v;
#pragma unroll
                for (int o = 0; o < 8; ++o) {
                    float f = b1[o];
#pragma unroll
                    for (int i = 0; i < 8; ++i) f += s[i] * w1[o * 8 + i];
                    f = fmaxf(f, 0.f);
                    acc2 += f * w2[o];
                }
                rp[r] = fmaxf(acc2, 0.f);
            }
            *(float4*)&mout[(size_t)(n0 + nh * 16 + lr) * LL + l0 + lg * 4] = res;
        }
    }
}

// ---------------------------------------------------------------------------
// f32 LayerNorm over C=256 (r17 proven).
// ---------------------------------------------------------------------------
__global__ __launch_bounds__(256) void ln_f32(
    const float* __restrict__ a, const float* __restrict__ g,
    const float* __restrict__ be, float* __restrict__ out)
{
    int lane = threadIdx.x & 63, wave = threadIdx.x >> 6;
    int row = blockIdx.x * 4 + wave;
    float4 v = *(const float4*)(a + (size_t)row * CC + lane * 4);
    float sum = v.x + v.y + v.z + v.w;
    float sq = v.x * v.x + v.y * v.y + v.z * v.z + v.w * v.w;
#pragma unroll
    for (int mk = 1; mk < 64; mk <<= 1) {
        sum += __shfl_xor(sum, mk);
        sq += __shfl_xor(sq, mk);
    }
    float mean = sum * (1.f / 256.f);
    float var = sq * (1.f / 256.f) - mean * mean;
    float rstd = rsqrtf(var + 1e-5f);
    int c = lane * 4;
    float4 ov;
    ov.x = (v.x - mean) * rstd * g[c + 0] + be[c + 0];
    ov.y = (v.y - mean) * rstd * g[c + 1] + be[c + 1];
    ov.z = (v.z - mean) * rstd * g[c + 2] + be[c + 2];
    ov.w = (v.w - mean) * rstd * g[c + 3] + be[c + 3];
    *(float4*)(out + (size_t)row * CC + c) = ov;
}

// ---------------------------------------------------------------------------
extern "C" void kernel_launch(void* const* d_in, const int* in_sizes, int n_in,
                              void* d_out, int out_size, void* d_ws, size_t ws_size,
                              hipStream_t stream)
{
    (void)in_sizes; (void)n_in; (void)out_size;
    float* outx = (float*)d_out;
    float* outm = outx + (size_t)BB * NN * CC;

    const float* query     = (const float*)d_in[0];
    const float* key       = (const float*)d_in[1];
    const float* value     = (const float*)d_in[2];
    const float* sa_qkv_w  = (const float*)d_in[3];
    const float* sa_proj_w = (const float*)d_in[4];
    const float* sa_proj_b = (const float*)d_in[5];
    const float* norm3_g   = (const float*)d_in[6];
    const float* norm3_b   = (const float*)d_in[7];
    const float* q_w       = (const float*)d_in[8];
    const float* k_w       = (const float*)d_in[9];
    const float* v_w       = (const float*)d_in[10];
    const float* ca_proj_w = (const float*)d_in[11];
    const float* ca_proj_b = (const float*)d_in[12];
    const float* l1_w      = (const float*)d_in[13];
    const float* l1_b      = (const float*)d_in[14];
    const float* l2_w      = (const float*)d_in[15];
    const float* l2_b      = (const float*)d_in[16];
    const float* ln1_g     = (const float*)d_in[17];
    const float* ln1_b     = (const float*)d_in[18];
    const float* ln2_g     = (const float*)d_in[19];
    const float* ln2_b     = (const float*)d_in[20];
    const float* fc1_w     = (const float*)d_in[21];
    const float* fc1_b     = (const float*)d_in[22];
    const float* fc2_w     = (const float*)d_in[23];
    const float* fc2_b     = (const float*)d_in[24];

    const int NSPLIT = 8;

    char* w0 = (char*)d_ws;
    char* unionA = w0;                 w0 += (size_t)16 * 1024 * 1024;
    float* saH = (float*)w0;           w0 += (size_t)1024 * 256 * 4;
    float* x1  = (float*)w0;           w0 += (size_t)1024 * 256 * 4;
    float* x2  = (float*)w0;           w0 += (size_t)1024 * 256 * 4;
    float* tmp = (float*)w0;           w0 += (size_t)1024 * 256 * 4;
    float* caH = (float*)w0;           w0 += (size_t)1024 * 256 * 4;
    u16*   qc_b = (u16*)w0;            w0 += (size_t)1024 * 256 * 2;
    float* po  = (float*)w0;           w0 += (size_t)NSPLIT * 512 * 256 * 4;
    float* pm  = (float*)w0;           w0 += (size_t)NSPLIT * 512 * 8 * 4;
    float* ps  = (float*)w0;           w0 += (size_t)NSPLIT * 512 * 8 * 4;
    size_t need = (size_t)(w0 - (char*)d_ws);
    u16* qkv_b = (u16*)unionA;                                   // 1024 x 768
    u16* vst   = (u16*)(unionA + (size_t)1024 * 768 * 2);        // (B,H,D,512)
    u16* kc_b  = (u16*)unionA;                                   // 8192 x 256
    u16* vc_b  = (u16*)(unionA + (size_t)8192 * 256 * 2);        // 8192 x 256
    u16* vt_b  = (u16*)(unionA + (size_t)2 * 8192 * 256 * 2);    // (H,D,8192)
    float* hb  = (float*)unionA;                                 // 1024 x 1024

    if (ws_size < need) {
        sentinel<<<dim3(1), dim3(64), 0, stream>>>(outx, 1000.f + (float)(ws_size >> 20));
        return;
    }

    dim3 blk(256);

    // 1. qkv (bf16) = query @ sa_qkv_w.T
    gemm_ml<0, 0, false, 1><<<dim3(16, 12), blk, 0, stream>>>(query, sa_qkv_w, nullptr, nullptr, nullptr, qkv_b, 1024, 768, 256);
    // 2. self V^T
    transpose_bf<<<dim3(8, 8, 2), blk, 0, stream>>>(qkv_b + 512, vst, 768, 512, (size_t)512 * 768, (size_t)8 * 32 * 512);
    // 3. self attention (MFMA) -> saH
    attn_mfma<false><<<dim3(16, 8, 2), blk, 0, stream>>>(qkv_b, qkv_b + 256, vst, saH, nullptr, nullptr, 512, 768, 768, 512, 512);
    // 4. sa proj + bias + residual(query) -> tmp
    gemm_ml<1, 0, true, 0><<<dim3(16, 4), blk, 0, stream>>>(saH, sa_proj_w, sa_proj_b, query, tmp, nullptr, 1024, 256, 256);
    // 5. LN(norm3) -> x1
    ln_f32<<<dim3(256), blk, 0, stream>>>(tmp, norm3_g, norm3_b, x1);
    // 6. qc (bf16) = x1 @ q_w.T
    gemm_ml<0, 0, false, 1><<<dim3(16, 4), blk, 0, stream>>>(x1, q_w, nullptr, nullptr, nullptr, qc_b, 1024, 256, 256);
    // 7-10. per-batch
    for (int b = 0; b < 2; ++b) {
        const float* keyb = key + (size_t)b * 8192 * 256;
        const float* valb = value + (size_t)b * 8192 * 256;
        const u16* qcb = qc_b + (size_t)b * 512 * 256;
        gemm_ml<0, 0, false, 1><<<dim3(128, 4), blk, 0, stream>>>(keyb, k_w, nullptr, nullptr, nullptr, kc_b, 8192, 256, 256);
        gemm_ml<0, 0, false, 1><<<dim3(128, 4), blk, 0, stream>>>(valb, v_w, nullptr, nullptr, nullptr, vc_b, 8192, 256, 256);
        transpose_bf<<<dim3(128, 8, 1), blk, 0, stream>>>(vc_b, vt_b, 256, 8192, 0, 0);
        attn_mfma<true><<<dim3(16, 8, NSPLIT), blk, 0, stream>>>(qcb, kc_b, vt_b, po, pm, ps, 8192, 256, 256, 8192, 512);
        attn_combine<<<dim3(512), blk, 0, stream>>>(po, pm, ps, caH + (size_t)b * 512 * 256, 512, NSPLIT);
        smask_mfma<4><<<dim3(32, 16), blk, 0, stream>>>(qcb, kc_b, l1_w, l1_b, l2_w, l2_b,
                                                        outm + (size_t)b * 512 * 8192);
    }
    // 11. ca proj + bias + residual(x1) -> tmp
    gemm_ml<1, 0, true, 0><<<dim3(16, 4), blk, 0, stream>>>(caH, ca_proj_w, ca_proj_b, x1, tmp, nullptr, 1024, 256, 256);
    // 12. LN(ln1) -> x2
    ln_f32<<<dim3(256), blk, 0, stream>>>(tmp, ln1_g, ln1_b, x2);
    // 13. fc1 + bias + GELU -> hb
    gemm_ml<0, 1, true, 0><<<dim3(16, 16), blk, 0, stream>>>(x2, fc1_w, fc1_b, nullptr, hb, nullptr, 1024, 1024, 256);
    // 14. fc2 + bias + residual(x2) -> tmp (K=1024)
    gemm_ml<1, 0, true, 0><<<dim3(16, 4), blk, 0, stream>>>(hb, fc2_w, fc2_b, x2, tmp, nullptr, 1024, 256, 1024);
    // 15. LN(ln2) -> outx
    ln_f32<<<dim3(256), blk, 0, stream>>>(tmp, ln2_g, ln2_b, outx);
}

// Round 26
// 179.416 us; speedup vs baseline: 1.9778x; 1.2065x over previous
//
#include <hip/hip_runtime.h>
#include <hip/hip_bf16.h>

#define BB 2
#define NN 512
#define LL 8192
#define CC 256
#define HH 8
#define DD 32
#define SCALE 0.17677669529663687f
#define NSPLIT 8

typedef unsigned short u16;
typedef unsigned int u32;
typedef __attribute__((ext_vector_type(8))) short bf16x8;
typedef __attribute__((ext_vector_type(4))) float f32x4;

__device__ __forceinline__ float bf2f(u16 v) { return __uint_as_float(((u32)v) << 16); }
__device__ __forceinline__ u16 f2bf(float f) {
    u32 u = __float_as_uint(f);
    return (u16)((u + 0x7fffu + ((u >> 16) & 1u)) >> 16);
}
__device__ __forceinline__ bf16x8 ld8(const u16* p) { return *(const bf16x8*)p; }
__device__ __forceinline__ uint2 pack4(float4 v) {
    uint2 p;
    p.x = (u32)f2bf(v.x) | ((u32)f2bf(v.y) << 16);
    p.y = (u32)f2bf(v.z) | ((u32)f2bf(v.w) << 16);
    return p;
}

__global__ void sentinel(float* out, float val) {
    if (threadIdx.x == 0) out[0] = val;
}

// ---------------------------------------------------------------------------
// LDS-staged MFMA GEMM with 1-deep register prefetch (r25 proven).
// OUT: 0 f32, 1 bf16, 2 both.
// ---------------------------------------------------------------------------
template <int RES, int ACT, bool HAS_BIAS, int OUT>
__global__ __launch_bounds__(256) void gemm_ml(
    const float* __restrict__ A, const float* __restrict__ W,
    const float* __restrict__ bias, const float* __restrict__ res,
    float* __restrict__ Cf, u16* __restrict__ Cb, int M, int N, int K)
{
    __shared__ alignas(16) u16 As[64][40], Ws[64][40];
    int t = threadIdx.x;
    int lane = t & 63, wave = t >> 6;
    int lr = lane & 15, lg = lane >> 4;
    int m0 = blockIdx.x * 64, n0 = blockIdx.y * 64;
    int srow = t >> 3, sc4 = (t & 7) * 4;
    const float* pa0 = &A[(size_t)(m0 + srow) * K + sc4];
    const float* pa1 = &A[(size_t)(m0 + 32 + srow) * K + sc4];
    const float* pw0 = &W[(size_t)(n0 + srow) * K + sc4];
    const float* pw1 = &W[(size_t)(n0 + 32 + srow) * K + sc4];
    float4 ra0 = *(const float4*)(pa0);
    float4 ra1 = *(const float4*)(pa1);
    float4 rw0 = *(const float4*)(pw0);
    float4 rw1 = *(const float4*)(pw1);
    f32x4 acc[4] = {};
    for (int k0 = 0; k0 < K; k0 += 32) {
        *(uint2*)&As[srow][sc4]      = pack4(ra0);
        *(uint2*)&As[srow + 32][sc4] = pack4(ra1);
        *(uint2*)&Ws[srow][sc4]      = pack4(rw0);
        *(uint2*)&Ws[srow + 32][sc4] = pack4(rw1);
        __syncthreads();
        if (k0 + 32 < K) {
            ra0 = *(const float4*)(pa0 + k0 + 32);
            ra1 = *(const float4*)(pa1 + k0 + 32);
            rw0 = *(const float4*)(pw0 + k0 + 32);
            rw1 = *(const float4*)(pw1 + k0 + 32);
        }
        bf16x8 af = ld8(&As[wave * 16 + lr][lg * 8]);
#pragma unroll
        for (int nt = 0; nt < 4; ++nt) {
            bf16x8 wf = ld8(&Ws[nt * 16 + lr][lg * 8]);
            acc[nt] = __builtin_amdgcn_mfma_f32_16x16x32_bf16(af, wf, acc[nt], 0, 0, 0);
        }
        __syncthreads();
    }
#pragma unroll
    for (int nt = 0; nt < 4; ++nt) {
        int col = n0 + nt * 16 + lr;
        float bv = HAS_BIAS ? bias[col] : 0.f;
#pragma unroll
        for (int r = 0; r < 4; ++r) {
            int row = m0 + wave * 16 + lg * 4 + r;
            float v = acc[nt][r] + bv;
            if (RES) v += res[(size_t)row * N + col];
            if (ACT) v = 0.5f * v * (1.f + erff(v * 0.70710678118f));
            if (OUT == 0 || OUT == 2) Cf[(size_t)row * N + col] = v;
            if (OUT == 1 || OUT == 2) Cb[(size_t)row * N + col] = f2bf(v);
        }
    }
}

// ---------------------------------------------------------------------------
// bf16 head-transpose (r20 proven), batch via blockIdx.z.
// ---------------------------------------------------------------------------
__global__ __launch_bounds__(256) void transpose_bf(
    const u16* __restrict__ in, u16* __restrict__ out,
    int rowStride, int vtL, size_t bStrideIn, size_t bStrideOut)
{
    __shared__ alignas(16) u16 tl[64][33];
    int r0 = blockIdx.x * 64;
    int h = blockIdx.y, b = blockIdx.z;
    const u16* ip = in + (size_t)b * bStrideIn + h * DD;
    for (int i = threadIdx.x; i < 64 * 32; i += 256) {
        int r = i >> 5, d = i & 31;
        tl[r][d] = ip[(size_t)(r0 + r) * rowStride + d];
    }
    __syncthreads();
    u16* op = out + (size_t)b * bStrideOut + (size_t)h * DD * vtL + r0;
    for (int i = threadIdx.x; i < 64 * 32; i += 256) {
        int r = i & 63, d = i >> 6;
        op[(size_t)d * vtL + r] = tl[r][d];
    }
}

// ---------------------------------------------------------------------------
// MFMA flash attention (r20 proven). SPLIT: blockIdx.z = b*NSPLIT + split,
// writes per-(b,split) partials. !SPLIT: blockIdx.z = batch, direct output.
// ---------------------------------------------------------------------------
template <bool SPLIT>
__global__ __launch_bounds__(256) void attn_mfma(
    const u16* __restrict__ qp, const u16* __restrict__ kp,
    const u16* __restrict__ vt, float* __restrict__ outp,
    float* __restrict__ pm, float* __restrict__ ps_,
    int Lk, int qStride, int kStride, int vtL, int Nq)
{
    __shared__ alignas(16) u16 plds[4][32][48];
    __shared__ alignas(16) float comb[4][32][34];
    int lane = threadIdx.x & 63, wave = threadIdx.x >> 6;
    int lr = lane & 15, lg = lane >> 4;
    int h = blockIdx.y, n0 = blockIdx.x * 32, z = blockIdx.z;
    size_t qoff, koff, voff;
    int lbeg, lend;
    if (SPLIT) {
        int b = z >> 3, split = z & (NSPLIT - 1);
        int chunk = Lk / (NSPLIT * 4);
        lbeg = split * (Lk / NSPLIT) + wave * chunk;
        lend = lbeg + chunk;
        qoff = (size_t)b * Nq * qStride;
        koff = (size_t)b * Lk * kStride;
        voff = (size_t)b * HH * DD * vtL;
    } else {
        int chunk = Lk / 4;
        lbeg = wave * chunk;
        lend = lbeg + chunk;
        qoff = (size_t)z * Nq * qStride;
        koff = (size_t)z * Lk * kStride;
        voff = (size_t)z * HH * DD * vtL;
    }

    bf16x8 bq[2];
#pragma unroll
    for (int nh = 0; nh < 2; ++nh)
        bq[nh] = ld8(qp + qoff + (size_t)(n0 + nh * 16 + lr) * qStride + h * DD + lg * 8);

    f32x4 o[2][2] = {};
    float m = -1e30f, s = 0.f;
    float m2 = -1e30f, s2 = 0.f;
    const u16* kb = kp + koff + h * DD + lg * 8;
    const u16* vb0 = vt + voff + (size_t)h * DD * vtL;

    for (int l0 = lbeg; l0 < lend; l0 += 32) {
        bf16x8 ka[2];
#pragma unroll
        for (int lt = 0; lt < 2; ++lt)
            ka[lt] = ld8(kb + (size_t)(l0 + lt * 16 + lr) * kStride);
        f32x4 st[2][2];
#pragma unroll
        for (int lt = 0; lt < 2; ++lt)
#pragma unroll
            for (int nh = 0; nh < 2; ++nh) {
                f32x4 zz = {0.f, 0.f, 0.f, 0.f};
                st[lt][nh] = __builtin_amdgcn_mfma_f32_16x16x32_bf16(ka[lt], bq[nh], zz, 0, 0, 0);
            }
        float aq[2];
#pragma unroll
        for (int nh = 0; nh < 2; ++nh) {
            float mprev = (nh == 0) ? m : m2;
            float sprev = (nh == 0) ? s : s2;
            float mx = -1e30f;
#pragma unroll
            for (int lt = 0; lt < 2; ++lt)
#pragma unroll
                for (int r = 0; r < 4; ++r) {
                    float v = st[lt][nh][r] * SCALE;
                    st[lt][nh][r] = v;
                    mx = fmaxf(mx, v);
                }
            mx = fmaxf(mx, __shfl_xor(mx, 16));
            mx = fmaxf(mx, __shfl_xor(mx, 32));
            float mn = fmaxf(mprev, mx);
            float alpha = __expf(mprev - mn);
            float rs = 0.f;
#pragma unroll
            for (int lt = 0; lt < 2; ++lt) {
                u16 pk[4];
#pragma unroll
                for (int r = 0; r < 4; ++r) {
                    float p = __expf(st[lt][nh][r] - mn);
                    rs += p;
                    pk[r] = f2bf(p);
                }
                uint2 pv;
                pv.x = (u32)pk[0] | ((u32)pk[1] << 16);
                pv.y = (u32)pk[2] | ((u32)pk[3] << 16);
                *(uint2*)&plds[wave][nh * 16 + lr][lt * 16 + lg * 4] = pv;
            }
            rs += __shfl_xor(rs, 16);
            rs += __shfl_xor(rs, 32);
            if (nh == 0) { s = sprev * alpha + rs; m = mn; }
            else         { s2 = sprev * alpha + rs; m2 = mn; }
            aq[nh] = alpha;
        }
#pragma unroll
        for (int qt = 0; qt < 2; ++qt)
#pragma unroll
            for (int r = 0; r < 4; ++r) {
                float al = __shfl(aq[qt], (lg << 2) + r);
                o[qt][0][r] *= al;
                o[qt][1][r] *= al;
            }
        asm volatile("" ::: "memory");
        bf16x8 pa[2], vv[2];
#pragma unroll
        for (int qt = 0; qt < 2; ++qt)
            pa[qt] = ld8(&plds[wave][qt * 16 + lr][lg * 8]);
        asm volatile("" ::: "memory");
#pragma unroll
        for (int dt = 0; dt < 2; ++dt)
            vv[dt] = ld8(vb0 + (size_t)(dt * 16 + lr) * vtL + l0 + lg * 8);
#pragma unroll
        for (int qt = 0; qt < 2; ++qt)
#pragma unroll
            for (int dt = 0; dt < 2; ++dt)
                o[qt][dt] = __builtin_amdgcn_mfma_f32_16x16x32_bf16(pa[qt], vv[dt], o[qt][dt], 0, 0, 0);
    }

#pragma unroll
    for (int qt = 0; qt < 2; ++qt)
#pragma unroll
        for (int dt = 0; dt < 2; ++dt)
#pragma unroll
            for (int r = 0; r < 4; ++r)
                comb[wave][qt * 16 + lg * 4 + r][dt * 16 + lr] = o[qt][dt][r];
    if (lg == 0) {
        comb[wave][lr][32] = m;       comb[wave][lr][33] = s;
        comb[wave][16 + lr][32] = m2; comb[wave][16 + lr][33] = s2;
    }
    __syncthreads();
    for (int idx = threadIdx.x; idx < 1024; idx += 256) {
        int q2 = idx >> 5, d = idx & 31;
        float mm = -1e30f;
#pragma unroll
        for (int w = 0; w < 4; ++w) mm = fmaxf(mm, comb[w][q2][32]);
        float num = 0.f, den = 0.f;
#pragma unroll
        for (int w = 0; w < 4; ++w) {
            float e = __expf(comb[w][q2][32] - mm);
            num += e * comb[w][q2][d];
            den += e * comb[w][q2][33];
        }
        int n = n0 + q2;
        if (SPLIT) {
            outp[((size_t)z * Nq + n) * CC + h * DD + d] = num;
            if (d == 0) {
                pm[((size_t)z * Nq + n) * HH + h] = mm;
                ps_[((size_t)z * Nq + n) * HH + h] = den;
            }
        } else {
            outp[((size_t)z * Nq + n) * CC + h * DD + d] = num / den;
        }
    }
}

// ---------------------------------------------------------------------------
// Combine NSPLIT flash partials per batch (blockIdx.z = batch).
// ---------------------------------------------------------------------------
__global__ __launch_bounds__(256) void attn_combine(
    const float* __restrict__ po, const float* __restrict__ pm,
    const float* __restrict__ ps, float* __restrict__ out, int Nq)
{
    int idx = blockIdx.x * 256 + threadIdx.x;
    if (idx >= Nq * CC) return;
    int b = blockIdx.z;
    int n = idx >> 8, cd = idx & 255;
    int h = cd >> 5;
    float mm = -1e30f;
    for (int zz = 0; zz < NSPLIT; ++zz)
        mm = fmaxf(mm, pm[((size_t)(b * NSPLIT + zz) * Nq + n) * HH + h]);
    float num = 0.f, den = 0.f;
    for (int zz = 0; zz < NSPLIT; ++zz) {
        int pz = b * NSPLIT + zz;
        float e = __expf(pm[((size_t)pz * Nq + n) * HH + h] - mm);
        num += e * po[((size_t)pz * Nq + n) * CC + cd];
        den += e * ps[((size_t)pz * Nq + n) * HH + h];
    }
    out[((size_t)b * Nq + n) * CC + cd] = num / den;
}

// ---------------------------------------------------------------------------
// MFMA mask (r21 proven), batch via blockIdx.z.
// ---------------------------------------------------------------------------
template <int NL>
__global__ __launch_bounds__(256) void smask_mfma(
    const u16* __restrict__ qcb, const u16* __restrict__ kcb,
    const float* __restrict__ w1, const float* __restrict__ b1,
    const float* __restrict__ w2, const float* __restrict__ b2,
    float* __restrict__ mout)
{
    int lane = threadIdx.x & 63, wave = threadIdx.x >> 6;
    int lr = lane & 15, lg = lane >> 4;
    int n0 = blockIdx.y * 32, b = blockIdx.z;
    const u16* qp = qcb + (size_t)b * NN * CC;
    const u16* kp = kcb + (size_t)b * LL * CC;
    float* mp = mout + (size_t)b * NN * LL;
    bf16x8 bq[8][2];
#pragma unroll
    for (int h = 0; h < 8; ++h)
#pragma unroll
        for (int nh = 0; nh < 2; ++nh)
            bq[h][nh] = ld8(qp + (size_t)(n0 + nh * 16 + lr) * CC + h * DD + lg * 8);
    float b2v = b2[0];
    for (int it = 0; it < NL; ++it) {
        int l0 = (blockIdx.x * NL + it) * 64 + wave * 16;
        bf16x8 ka[8];
#pragma unroll
        for (int h = 0; h < 8; ++h)
            ka[h] = ld8(kp + (size_t)(l0 + lr) * CC + h * DD + lg * 8);
#pragma unroll
        for (int nh = 0; nh < 2; ++nh) {
            f32x4 st[8];
#pragma unroll
            for (int h = 0; h < 8; ++h) {
                f32x4 zz = {0.f, 0.f, 0.f, 0.f};
                st[h] = __builtin_amdgcn_mfma_f32_16x16x32_bf16(ka[h], bq[h][nh], zz, 0, 0, 0);
            }
            float4 res;
            float* rp = &res.x;
#pragma unroll
            for (int r = 0; r < 4; ++r) {
                float s[8];
#pragma unroll
                for (int i = 0; i < 8; ++i) s[i] = st[i][r] * SCALE;
                float acc2 = b2v;
#pragma unroll
                for (int o = 0; o < 8; ++o) {
                    float f = b1[o];
#pragma unroll
                    for (int i = 0; i < 8; ++i) f += s[i] * w1[o * 8 + i];
                    f = fmaxf(f, 0.f);
                    acc2 += f * w2[o];
                }
                rp[r] = fmaxf(acc2, 0.f);
            }
            *(float4*)&mp[(size_t)(n0 + nh * 16 + lr) * LL + l0 + lg * 4] = res;
        }
    }
}

// ---------------------------------------------------------------------------
// f32 LayerNorm over C=256 (r17 proven).
// ---------------------------------------------------------------------------
__global__ __launch_bounds__(256) void ln_f32(
    const float* __restrict__ a, const float* __restrict__ g,
    const float* __restrict__ be, float* __restrict__ out)
{
    int lane = threadIdx.x & 63, wave = threadIdx.x >> 6;
    int row = blockIdx.x * 4 + wave;
    float4 v = *(const float4*)(a + (size_t)row * CC + lane * 4);
    float sum = v.x + v.y + v.z + v.w;
    float sq = v.x * v.x + v.y * v.y + v.z * v.z + v.w * v.w;
#pragma unroll
    for (int mk = 1; mk < 64; mk <<= 1) {
        sum += __shfl_xor(sum, mk);
        sq += __shfl_xor(sq, mk);
    }
    float mean = sum * (1.f / 256.f);
    float var = sq * (1.f / 256.f) - mean * mean;
    float rstd = rsqrtf(var + 1e-5f);
    int c = lane * 4;
    float4 ov;
    ov.x = (v.x - mean) * rstd * g[c + 0] + be[c + 0];
    ov.y = (v.y - mean) * rstd * g[c + 1] + be[c + 1];
    ov.z = (v.z - mean) * rstd * g[c + 2] + be[c + 2];
    ov.w = (v.w - mean) * rstd * g[c + 3] + be[c + 3];
    *(float4*)(out + (size_t)row * CC + c) = ov;
}

// ---------------------------------------------------------------------------
extern "C" void kernel_launch(void* const* d_in, const int* in_sizes, int n_in,
                              void* d_out, int out_size, void* d_ws, size_t ws_size,
                              hipStream_t stream)
{
    (void)in_sizes; (void)n_in; (void)out_size;
    float* outx = (float*)d_out;
    float* outm = outx + (size_t)BB * NN * CC;

    const float* query     = (const float*)d_in[0];
    const float* key       = (const float*)d_in[1];
    const float* value     = (const float*)d_in[2];
    const float* sa_qkv_w  = (const float*)d_in[3];
    const float* sa_proj_w = (const float*)d_in[4];
    const float* sa_proj_b = (const float*)d_in[5];
    const float* norm3_g   = (const float*)d_in[6];
    const float* norm3_b   = (const float*)d_in[7];
    const float* q_w       = (const float*)d_in[8];
    const float* k_w       = (const float*)d_in[9];
    const float* v_w       = (const float*)d_in[10];
    const float* ca_proj_w = (const float*)d_in[11];
    const float* ca_proj_b = (const float*)d_in[12];
    const float* l1_w      = (const float*)d_in[13];
    const float* l1_b      = (const float*)d_in[14];
    const float* l2_w      = (const float*)d_in[15];
    const float* l2_b      = (const float*)d_in[16];
    const float* ln1_g     = (const float*)d_in[17];
    const float* ln1_b     = (const float*)d_in[18];
    const float* ln2_g     = (const float*)d_in[19];
    const float* ln2_b     = (const float*)d_in[20];
    const float* fc1_w     = (const float*)d_in[21];
    const float* fc1_b     = (const float*)d_in[22];
    const float* fc2_w     = (const float*)d_in[23];
    const float* fc2_b     = (const float*)d_in[24];

    char* w0 = (char*)d_ws;
    char* unionA = w0;                 w0 += (size_t)24 * 1024 * 1024;   // kc2+vc2+vt2
    float* saH = (float*)w0;           w0 += (size_t)1024 * 256 * 4;
    float* x1  = (float*)w0;           w0 += (size_t)1024 * 256 * 4;
    float* x2  = (float*)w0;           w0 += (size_t)1024 * 256 * 4;
    float* tmp = (float*)w0;           w0 += (size_t)1024 * 256 * 4;
    float* caH = (float*)w0;           w0 += (size_t)1024 * 256 * 4;
    u16*   qc_b = (u16*)w0;            w0 += (size_t)1024 * 256 * 2;
    float* po  = (float*)w0;           w0 += (size_t)2 * NSPLIT * 512 * 256 * 4;  // 8 MB
    float* pm  = (float*)w0;           w0 += (size_t)2 * NSPLIT * 512 * 8 * 4;
    float* ps  = (float*)w0;           w0 += (size_t)2 * NSPLIT * 512 * 8 * 4;
    size_t need = (size_t)(w0 - (char*)d_ws);
    // unionA phase 1: qkv_b (1.5MB) + vst (0.5MB); phase 2: kc2 (8MB) + vc2
    // (8MB) + vt2 (8MB); phase 3: hb (4MB)
    u16* qkv_b = (u16*)unionA;                                     // 1024 x 768
    u16* vst   = (u16*)(unionA + (size_t)1024 * 768 * 2);          // (B,H,D,512)
    u16* kc_b2 = (u16*)unionA;                                     // 16384 x 256
    u16* vc_b2 = (u16*)(unionA + (size_t)16384 * 256 * 2);         // 16384 x 256
    u16* vt_b2 = (u16*)(unionA + (size_t)2 * 16384 * 256 * 2);     // (B,H,D,8192)
    float* hb  = (float*)unionA;                                   // 1024 x 1024

    if (ws_size < need) {
        sentinel<<<dim3(1), dim3(64), 0, stream>>>(outx, 1000.f + (float)(ws_size >> 20));
        return;
    }

    dim3 blk(256);

    // 1. qkv (bf16) = query @ sa_qkv_w.T
    gemm_ml<0, 0, false, 1><<<dim3(16, 12), blk, 0, stream>>>(query, sa_qkv_w, nullptr, nullptr, nullptr, qkv_b, 1024, 768, 256);
    // 2. self V^T
    transpose_bf<<<dim3(8, 8, 2), blk, 0, stream>>>(qkv_b + 512, vst, 768, 512, (size_t)512 * 768, (size_t)8 * 32 * 512);
    // 3. self attention (MFMA) -> saH
    attn_mfma<false><<<dim3(16, 8, 2), blk, 0, stream>>>(qkv_b, qkv_b + 256, vst, saH, nullptr, nullptr, 512, 768, 768, 512, 512);
    // 4. sa proj + bias + residual(query) -> tmp
    gemm_ml<1, 0, true, 0><<<dim3(16, 4), blk, 0, stream>>>(saH, sa_proj_w, sa_proj_b, query, tmp, nullptr, 1024, 256, 256);
    // 5. LN(norm3) -> x1
    ln_f32<<<dim3(256), blk, 0, stream>>>(tmp, norm3_g, norm3_b, x1);
    // 6. qc (bf16) = x1 @ q_w.T
    gemm_ml<0, 0, false, 1><<<dim3(16, 4), blk, 0, stream>>>(x1, q_w, nullptr, nullptr, nullptr, qc_b, 1024, 256, 256);
    // 7. kc/vc for BOTH batches (key/value are batch-contiguous: M=16384)
    gemm_ml<0, 0, false, 1><<<dim3(256, 4), blk, 0, stream>>>(key, k_w, nullptr, nullptr, nullptr, kc_b2, 16384, 256, 256);
    gemm_ml<0, 0, false, 1><<<dim3(256, 4), blk, 0, stream>>>(value, v_w, nullptr, nullptr, nullptr, vc_b2, 16384, 256, 256);
    // 8. V^T both batches
    transpose_bf<<<dim3(128, 8, 2), blk, 0, stream>>>(vc_b2, vt_b2, 256, 8192, (size_t)8192 * 256, (size_t)8 * 32 * 8192);
    // 9. cross attention both batches (z = b*NSPLIT + split)
    attn_mfma<true><<<dim3(16, 8, 2 * NSPLIT), blk, 0, stream>>>(qc_b, kc_b2, vt_b2, po, pm, ps, 8192, 256, 256, 8192, 512);
    // 10. combine both batches
    attn_combine<<<dim3(512, 1, 2), blk, 0, stream>>>(po, pm, ps, caH, 512);
    // 11. mask both batches
    smask_mfma<4><<<dim3(32, 16, 2), blk, 0, stream>>>(qc_b, kc_b2, l1_w, l1_b, l2_w, l2_b, outm);
    // 12. ca proj + bias + residual(x1) -> tmp
    gemm_ml<1, 0, true, 0><<<dim3(16, 4), blk, 0, stream>>>(caH, ca_proj_w, ca_proj_b, x1, tmp, nullptr, 1024, 256, 256);
    // 13. LN(ln1) -> x2
    ln_f32<<<dim3(256), blk, 0, stream>>>(tmp, ln1_g, ln1_b, x2);
    // 14. fc1 + bias + GELU -> hb
    gemm_ml<0, 1, true, 0><<<dim3(16, 16), blk, 0, stream>>>(x2, fc1_w, fc1_b, nullptr, hb, nullptr, 1024, 1024, 256);
    // 15. fc2 + bias + residual(x2) -> tmp (K=1024)
    gemm_ml<1, 0, true, 0><<<dim3(16, 4), blk, 0, stream>>>(hb, fc2_w, fc2_b, x2, tmp, nullptr, 1024, 256, 1024);
    // 16. LN(ln2) -> outx
    ln_f32<<<dim3(256), blk, 0, stream>>>(tmp, ln2_g, ln2_b, outx);
}